// Round 3
// baseline (9065.084 us; speedup 1.0000x reference)
//
#include <hip/hip_runtime.h>
#include <hip/hip_bf16.h>
#include <math.h>

#define NMAX 200
#define EH 256
#define DH 512
#define NMIX 20
#define HE_BLK 131072   // 512*256
#define HD_BLK 262144   // 512*512

typedef unsigned short u16;
typedef __bf16 bfx8 __attribute__((ext_vector_type(8)));
typedef float  fx4  __attribute__((ext_vector_type(4)));
typedef u16    us8  __attribute__((ext_vector_type(8)));

__device__ __forceinline__ float sigm(float x) { return 1.0f / (1.0f + __expf(-x)); }
__device__ __forceinline__ u16 f2bf(float x) {
    unsigned u = __float_as_uint(x);
    unsigned r = u + 0x7fffu + ((u >> 16) & 1u);
    return (u16)(r >> 16);
}
__device__ __forceinline__ float bf2f(u16 h) { return __uint_as_float(((unsigned)h) << 16); }

// LDS tile index, XOR swizzle within 64-u16 (128B) rows: kills stride-128B bank conflicts
__device__ __forceinline__ int ldsidx(int r, int k) { return r * 64 + (k ^ ((r & 7) << 3)); }

__device__ __forceinline__ void stageA(u16* As, const u16* src, int stride) {
    int t = threadIdx.x;
    int r = t >> 3, k0 = (t & 7) * 8;
    *(us8*)&As[ldsidx(r, k0)] = *(const us8*)&src[r * stride + k0];
}
__device__ __forceinline__ void stageB(u16* Bs, const u16* wT, int K, int GS, int j0, int kbase) {
#pragma unroll
    for (int i = 0; i < 4; ++i) {
        int idx = i * 256 + threadIdx.x;
        int r = idx >> 3, k0 = (idx & 7) * 8;
        int n = (r >> 5) * GS + j0 + (r & 31);
        *(us8*)&Bs[ldsidx(r, k0)] = *(const us8*)&wT[n * K + kbase + k0];
    }
}
// 16-row B slice (out-head)
__device__ __forceinline__ void stageY(u16* Ys, const u16* wT, int nbase, int kb) {
    int t = threadIdx.x;
    if (t < 128) {
        int r = t >> 3, k0 = (t & 7) * 8;
        *(us8*)&Ys[ldsidx(r, k0)] = *(const us8*)&wT[(nbase + r) * 512 + kb + k0];
    }
}

// split-precision MFMA chunk (BK=64): 3 mfma per tile (hh, hl, lh)
__device__ __forceinline__ void gemm_chunk(const u16* As_hi, const u16* As_lo,
                                           const u16* Bs_hi, const u16* Bs_lo,
                                           int wv, int lane, fx4 acc[2][2]) {
    const int ar = lane & 15, kg = (lane >> 4) * 8;
#pragma unroll
    for (int ks = 0; ks < 2; ++ks) {
        const int kk = ks * 32 + kg;
        bfx8 ah[2], al[2], bh[2], bl[2];
#pragma unroll
        for (int mt = 0; mt < 2; ++mt) {
            int idx = ldsidx(mt * 16 + ar, kk);
            ah[mt] = *(const bfx8*)&As_hi[idx];
            al[mt] = *(const bfx8*)&As_lo[idx];
        }
#pragma unroll
        for (int nt = 0; nt < 2; ++nt) {
            int idx = ldsidx(wv * 32 + nt * 16 + ar, kk);
            bh[nt] = *(const bfx8*)&Bs_hi[idx];
            bl[nt] = *(const bfx8*)&Bs_lo[idx];
        }
#pragma unroll
        for (int mt = 0; mt < 2; ++mt)
#pragma unroll
            for (int nt = 0; nt < 2; ++nt) {
                acc[mt][nt] = __builtin_amdgcn_mfma_f32_16x16x32_bf16(ah[mt], bh[nt], acc[mt][nt], 0, 0, 0);
                acc[mt][nt] = __builtin_amdgcn_mfma_f32_16x16x32_bf16(ah[mt], bl[nt], acc[mt][nt], 0, 0, 0);
                acc[mt][nt] = __builtin_amdgcn_mfma_f32_16x16x32_bf16(al[mt], bh[nt], acc[mt][nt], 0, 0, 0);
            }
    }
}

// group barrier: sense-reversing, agent-scope. Relaxed spin + one acquire; release on arrive.
__device__ __forceinline__ void group_bar(unsigned* bar, unsigned nb) {
    __syncthreads();
    if (threadIdx.x == 0) {
        unsigned* cnt = bar;
        unsigned* gen = bar + 1;
        unsigned g = __hip_atomic_load(gen, __ATOMIC_RELAXED, __HIP_MEMORY_SCOPE_AGENT);
        unsigned old = __hip_atomic_fetch_add(cnt, 1u, __ATOMIC_ACQ_REL, __HIP_MEMORY_SCOPE_AGENT);
        if (old == nb - 1) {
            __hip_atomic_store(cnt, 0u, __ATOMIC_RELAXED, __HIP_MEMORY_SCOPE_AGENT);
            __hip_atomic_fetch_add(gen, 1u, __ATOMIC_RELEASE, __HIP_MEMORY_SCOPE_AGENT);
        } else {
            while (__hip_atomic_load(gen, __ATOMIC_RELAXED, __HIP_MEMORY_SCOPE_AGENT) == g)
                __builtin_amdgcn_s_sleep(2);
            (void)__hip_atomic_load(gen, __ATOMIC_ACQUIRE, __HIP_MEMORY_SCOPE_AGENT);
        }
    }
    __syncthreads();
}

// ---------------- prep: split fp32 weight [K][Nsrc] into transposed bf16 hi/lo [Nout][K] ----------------
__global__ __launch_bounds__(256) void prep_split_T(const float* __restrict__ src,
                                                    u16* dhi, u16* dlo, int K, int Nsrc, int Nout) {
    int idx = blockIdx.x * 256 + threadIdx.x;
    if (idx >= Nout * K) return;
    int n = idx / K, k = idx - n * K;
    float v = (n < Nsrc) ? src[k * Nsrc + n] : 0.0f;
    u16 hh = f2bf(v);
    dhi[idx] = hh;
    dlo[idx] = f2bf(v - bf2f(hh));
}

// ---------------- persistent encoder: 201 steps, 1 group-bar/step ----------------
// grid 256 = dir(2) x jx(8) x rt(16); group = (dir, rt): 8 blocks
__global__ __launch_bounds__(256) void enc_persist(
    const float* __restrict__ x,
    const float* __restrict__ Wih_f, const float* __restrict__ b_f,
    const float* __restrict__ Wih_b, const float* __restrict__ b_b,
    const u16* __restrict__ whhT, u16* __restrict__ he,
    unsigned* __restrict__ bar)
{
    const int bx = blockIdx.x;
    const int dir = bx >> 7, jx = (bx >> 4) & 7, rt = bx & 15;
    const int j0 = jx * 32, row0 = rt * 32;
    unsigned* mybar = bar + (dir * 16 + rt) * 32;

    const float* Wih  = dir ? Wih_b : Wih_f;
    const float* bias = dir ? b_b : b_f;
    const u16* wT_hi = whhT + (dir * 2 + 0) * 262144;
    const u16* wT_lo = whhT + (dir * 2 + 1) * 262144;

    __shared__ __align__(16) char smem[40960];
    u16* As_hi = (u16*)smem;
    u16* As_lo = As_hi + 2048;
    u16* Bs_hi = As_lo + 2048;
    u16* Bs_lo = Bs_hi + 8192;
    float (*gL)[32][32] = (float(*)[32][32])(smem + 8192);   // aliases Bs, used post-GEMM
    __shared__ float xL[32][5];

    const int tid = threadIdx.x;
    const int wv = tid >> 6, lane = tid & 63;
    const int j = tid & 31, rq = tid >> 5;

    float wih[5][4], bi4[4];
#pragma unroll
    for (int g = 0; g < 4; ++g) {
        bi4[g] = bias[g * 256 + j0 + j];
#pragma unroll
        for (int i = 0; i < 5; ++i) wih[i][g] = Wih[i * 1024 + g * 256 + j0 + j];
    }
    float c4[4] = {0.f, 0.f, 0.f, 0.f};

    for (int t = 0; t <= NMAX; ++t) {
        const int pb = t & 1, nb = pb ^ 1;
        const int ts = dir ? (NMAX - t) : t;
        const u16* hp_hi = he + ((pb * 2 + dir) * 2 + 0) * HE_BLK;
        const u16* hp_lo = he + ((pb * 2 + dir) * 2 + 1) * HE_BLK;
        u16* hn_hi = he + ((nb * 2 + dir) * 2 + 0) * HE_BLK;
        u16* hn_lo = he + ((nb * 2 + dir) * 2 + 1) * HE_BLK;

        if (tid < 160) xL[tid / 5][tid % 5] = x[ts * 2560 + (row0 + tid / 5) * 5 + tid % 5];

        fx4 acc[2][2] = {};
        for (int ch = 0; ch < 4; ++ch) {
            if (ch) __syncthreads();
            const int kb = ch * 64;
            stageA(As_hi, hp_hi + row0 * 256 + kb, 256);
            stageA(As_lo, hp_lo + row0 * 256 + kb, 256);
            stageB(Bs_hi, wT_hi, 256, 256, j0, kb);
            stageB(Bs_lo, wT_lo, 256, 256, j0, kb);
            __syncthreads();
            gemm_chunk(As_hi, As_lo, Bs_hi, Bs_lo, wv, lane, acc);
        }
        __syncthreads();
#pragma unroll
        for (int mt = 0; mt < 2; ++mt)
#pragma unroll
            for (int nt = 0; nt < 2; ++nt)
#pragma unroll
                for (int r2 = 0; r2 < 4; ++r2)
                    gL[wv][mt * 16 + (lane >> 4) * 4 + r2][nt * 16 + (lane & 15)] = acc[mt][nt][r2];
        __syncthreads();
#pragma unroll
        for (int ii = 0; ii < 4; ++ii) {
            const int b = rq + ii * 8;
            float gv[4];
#pragma unroll
            for (int g = 0; g < 4; ++g) {
                float s2 = gL[g][b][j] + bi4[g];
#pragma unroll
                for (int i = 0; i < 5; ++i) s2 += xL[b][i] * wih[i][g];
                gv[g] = s2;
            }
            float cv = c4[ii];
            cv = sigm(gv[1]) * cv + sigm(gv[0]) * tanhf(gv[2]);
            c4[ii] = cv;
            float hv = sigm(gv[3]) * tanhf(cv);
            const int gidx = (row0 + b) * 256 + j0 + j;
            u16 hh = f2bf(hv);
            hn_hi[gidx] = hh;
            hn_lo[gidx] = f2bf(hv - bf2f(hh));
        }
        group_bar(mybar, 8u);
    }
}

// ---------------- latent 1: mean/logvar/z ----------------
__global__ __launch_bounds__(256) void latent1(
    const u16* he,
    const float* __restrict__ W_mu, const float* __restrict__ b_mu,
    const float* __restrict__ W_lv, const float* __restrict__ b_lv,
    const float* __restrict__ eps, float* z, float* out)
{
    __shared__ float hs[16 * 512];
    const int row0 = blockIdx.x * 16;
    const int tid = threadIdx.x;
    const u16* hf_hi = he + ((1 * 2 + 0) * 2 + 0) * HE_BLK;
    const u16* hf_lo = he + ((1 * 2 + 0) * 2 + 1) * HE_BLK;
    const u16* hb_hi = he + ((1 * 2 + 1) * 2 + 0) * HE_BLK;
    const u16* hb_lo = he + ((1 * 2 + 1) * 2 + 1) * HE_BLK;
    for (int i = tid; i < 8192; i += 256) {
        int r = i >> 9, col = i & 511;
        int gi = (row0 + r) * 256;
        float v;
        if (col < 256) v = bf2f(hf_hi[gi + col]) + bf2f(hf_lo[gi + col]);
        else { int cc = col - 256; v = bf2f(hb_hi[gi + cc]) + bf2f(hb_lo[gi + cc]); }
        hs[i] = v;
    }
    __syncthreads();
    for (int p = tid; p < 2048; p += 256) {
        int r = p >> 7, cc = p & 127;
        const float* hr = hs + r * 512;
        float m = 0, lv = 0;
#pragma unroll 8
        for (int k = 0; k < 512; ++k) {
            float hv = hr[k];
            m  += hv * W_mu[k * 128 + cc];
            lv += hv * W_lv[k * 128 + cc];
        }
        m += b_mu[cc]; lv += b_lv[cc];
        int b = row0 + r;
        out[512002 + b * 128 + cc] = m;
        out[577538 + b * 128 + cc] = lv;
        z[b * 128 + cc] = m + __expf(0.5f * lv) * eps[b * 128 + cc];
    }
}

// ---------------- latent 2: h0/c0; zpre = z@dec_Wih[5:] + dec_b ----------------
__global__ __launch_bounds__(256) void latent2(
    const float* __restrict__ z, const float* __restrict__ W_fc, const float* __restrict__ b_fc,
    const float* __restrict__ dWih, const float* __restrict__ dec_b,
    u16* hd, float* c_d, float* zpre)
{
    __shared__ float zs[16 * 128];
    const int row0 = blockIdx.y * 16;
    const int tid = threadIdx.x;
    u16* h0_hi = hd + 0;
    u16* h0_lo = hd + HD_BLK;
    {
        float4* dst = (float4*)zs;
        const float4* src = (const float4*)(z + row0 * 128);
        for (int i = tid; i < 512; i += 256) dst[i] = src[i];
    }
    __syncthreads();
    const int colbase = blockIdx.x * 128;
    for (int p = tid; p < 16 * 128; p += 256) {
        int r = p >> 7, cl = p & 127;
        int col = colbase + cl;
        const float* zr = zs + r * 128;
        int b = row0 + r;
        if (col < 1024) {
            float acc = 0;
#pragma unroll 8
            for (int k = 0; k < 128; ++k) acc += zr[k] * W_fc[k * 1024 + col];
            float v = tanhf(acc + b_fc[col]);
            if (col < 512) {
                u16 hh = f2bf(v);
                h0_hi[b * 512 + col] = hh;
                h0_lo[b * 512 + col] = f2bf(v - bf2f(hh));
            } else c_d[b * 512 + (col - 512)] = v;
        } else {
            int n = col - 1024;
            float acc = 0;
#pragma unroll 8
            for (int k = 0; k < 128; ++k) acc += zr[k] * dWih[(5 + k) * 2048 + n];
            zpre[b * 2048 + n] = acc + dec_b[n];
        }
    }
}

// ---------------- persistent decoder: 200 iters, out-head de-duplicated via N-split ----------------
// grid 256 = jx(16) x rt(16); group = rt: 16 blocks. Barriers at bar + (32+rt)*32.
__global__ __launch_bounds__(256) void dec_persist(
    const float* __restrict__ x, const int* __restrict__ N_s,
    const float* __restrict__ dec_Wih, const float* __restrict__ b_out,
    const u16* __restrict__ whhT, const u16* __restrict__ woutT,
    const float* __restrict__ zpre, u16* __restrict__ hd,
    const float* __restrict__ c_init, float* __restrict__ ybuf,
    float* __restrict__ out, unsigned* __restrict__ bar)
{
    const int bx = blockIdx.x;
    const int jx = bx >> 4, rt = bx & 15;
    const int j0 = jx * 32, row0 = rt * 32;
    unsigned* mybar = bar + (32 + rt) * 32;
    const int ysbase = (jx * 8 > 112) ? 112 : jx * 8;   // 16-wide out tile start
    const int wlo = jx * 8, whi = (jx * 8 + 8 < 123) ? jx * 8 + 8 : 123;

    const u16* whh_hi = whhT;
    const u16* whh_lo = whhT + 1048576;
    const u16* wo_hi  = woutT;
    const u16* wo_lo  = woutT + 65536;

    __shared__ __align__(16) char smem[46080];
    u16* As_hi = (u16*)smem;                                  // 4KB
    u16* As_lo = As_hi + 2048;                                // 4KB
    u16* Bs_hi = As_lo + 2048;                                // 16KB
    u16* Bs_lo = Bs_hi + 8192;                                // 16KB
    u16* yBhi  = Bs_lo + 8192;                                // 2KB
    u16* yBlo  = yBhi + 1024;                                 // 2KB
    float (*gL)[32][32]   = (float(*)[32][32])(smem + 8192);  // aliases Bs_hi
    float (*yred)[32][16] = (float(*)[32][16])(smem);         // aliases As
    __shared__ float xtL[32][5], sxs[32][5], redL[64];
    __shared__ int lenL[32];

    const int tid = threadIdx.x;
    const int wv = tid >> 6, lane = tid & 63;
    const int j = tid & 31, rq = tid >> 5;

    // per-thread constants
    float dw[5][4];
#pragma unroll
    for (int g = 0; g < 4; ++g)
#pragma unroll
        for (int i = 0; i < 5; ++i) dw[i][g] = dec_Wih[i * 2048 + g * 512 + j0 + j];
    float c4[4];
#pragma unroll
    for (int ii = 0; ii < 4; ++ii) c4[ii] = c_init[(row0 + rq + ii * 8) * 512 + j0 + j];
    if (tid < 32) lenL[tid] = N_s[row0 + tid];
    if (tid < 160) sxs[tid / 5][tid % 5] = (tid % 5 == 2) ? 1.0f : 0.0f;  // stroke0

    for (int s = 0; s <= 199; ++s) {
        const bool do_y = (s > 0), do_cell = (s < 199);
        const int pb = s & 1, nb = pb ^ 1;
        const u16* hp_hi = hd + (pb * 2 + 0) * HD_BLK;
        const u16* hp_lo = hd + (pb * 2 + 1) * HD_BLK;
        u16* hn_hi = hd + (nb * 2 + 0) * HD_BLK;
        u16* hn_lo = hd + (nb * 2 + 1) * HD_BLK;

        if (do_y && tid < 160) xtL[tid / 5][tid % 5] = x[s * 2560 + (row0 + tid / 5) * 5 + tid % 5];

        fx4 acc[2][2] = {};
        fx4 accy[2] = {};
        for (int ch = 0; ch < 8; ++ch) {
            if (ch) __syncthreads();
            const int kb = ch * 64;
            stageA(As_hi, hp_hi + row0 * 512 + kb, 512);
            stageA(As_lo, hp_lo + row0 * 512 + kb, 512);
            if (do_cell) {
                stageB(Bs_hi, whh_hi, 512, 512, j0, kb);
                stageB(Bs_lo, whh_lo, 512, 512, j0, kb);
            }
            if (do_y) {
                stageY(yBhi, wo_hi, ysbase, kb);
                stageY(yBlo, wo_lo, ysbase, kb);
            }
            __syncthreads();
            if (do_cell) gemm_chunk(As_hi, As_lo, Bs_hi, Bs_lo, wv, lane, acc);
            if (do_y && wv < 2) {
                const int ar = lane & 15, kg = (lane >> 4) * 8;
                const int kk = wv * 32 + kg;
                bfx8 ybh = *(const bfx8*)&yBhi[ldsidx(ar, kk)];
                bfx8 ybl = *(const bfx8*)&yBlo[ldsidx(ar, kk)];
#pragma unroll
                for (int mt = 0; mt < 2; ++mt) {
                    int idx = ldsidx(mt * 16 + ar, kk);
                    bfx8 ah = *(const bfx8*)&As_hi[idx];
                    bfx8 al = *(const bfx8*)&As_lo[idx];
                    accy[mt] = __builtin_amdgcn_mfma_f32_16x16x32_bf16(ah, ybh, accy[mt], 0, 0, 0);
                    accy[mt] = __builtin_amdgcn_mfma_f32_16x16x32_bf16(ah, ybl, accy[mt], 0, 0, 0);
                    accy[mt] = __builtin_amdgcn_mfma_f32_16x16x32_bf16(al, ybh, accy[mt], 0, 0, 0);
                }
            }
        }
        __syncthreads();

        if (do_y) {
            if (wv < 2) {
#pragma unroll
                for (int mt = 0; mt < 2; ++mt)
#pragma unroll
                    for (int r2 = 0; r2 < 4; ++r2)
                        yred[wv][mt * 16 + (lane >> 4) * 4 + r2][lane & 15] = accy[mt][r2];
            }
            __syncthreads();
            for (int e = tid; e < 512; e += 256) {
                int r = e >> 4, cl = e & 15;
                int col = ysbase + cl;
                if (col >= wlo && col < whi) {
                    float v = yred[0][r][cl] + yred[1][r][cl] + b_out[col];
                    ybuf[(row0 + r) * 128 + col] = v;
                }
            }
            group_bar(mybar, 16u);   // y visible group-wide
            // mixture / losses / stroke (per-block, own rows; redundant across jx)
            {
                const int row = tid >> 3, g = tid & 7;
                const float* yr = ybuf + (row0 + row) * 128;
                const float dxv = xtL[row][0], dyv = xtL[row][1];
                float pm = -1e30f;
                for (int cg = g; cg < NMIX; cg += 8) pm = fmaxf(pm, yr[cg * 6]);
                pm = fmaxf(pm, __shfl_xor(pm, 1));
                pm = fmaxf(pm, __shfl_xor(pm, 2));
                pm = fmaxf(pm, __shfl_xor(pm, 4));
                float S = 0, gp = 0, gx = 0, gy = 0;
                for (int cg = g; cg < NMIX; cg += 8) {
                    float ph = yr[cg * 6], mux = yr[cg * 6 + 1], muy = yr[cg * 6 + 2];
                    float ssx = __expf(yr[cg * 6 + 3]), ssy = __expf(yr[cg * 6 + 4]);
                    float rho = tanhf(yr[cg * 6 + 5]);
                    float e = __expf(ph - pm);
                    float zx = (dxv - mux) / ssx, zy = (dyv - muy) / ssy;
                    float om = 1.0f - rho * rho;
                    float pdf = __expf(-(zx * zx + zy * zy - 2.0f * rho * zx * zy) / (2.0f * om))
                                * (0.15915494309189535f / (ssx * ssy * sqrtf(om)));
                    S += e; gp += e * pdf; gx += e * mux; gy += e * muy;
                }
#pragma unroll
                for (int off = 1; off < 8; off <<= 1) {
                    S += __shfl_xor(S, off); gp += __shfl_xor(gp, off);
                    gx += __shfl_xor(gx, off); gy += __shfl_xor(gy, off);
                }
                if (g == 0) {
                    const int b = row0 + row;
                    const int sy = s - 1;
                    float q0 = yr[120], q1 = yr[121], q2 = yr[122];
                    int len = lenL[row];
                    int am = 0; float bv = q0;
                    if (q1 > bv) { bv = q1; am = 1; }
                    if (q2 > bv) { bv = q2; am = 2; }
                    float s0, s1, s2, s3, s4;
                    if ((sy + 1) > len) { s0 = s1 = s2 = s3 = 0.0f; s4 = 1.0f; }
                    else { s0 = gx / S; s1 = gy / S; s2 = (am == 0); s3 = (am == 1); s4 = (am == 2); }
                    sxs[row][0] = s0; sxs[row][1] = s1; sxs[row][2] = s2; sxs[row][3] = s3; sxs[row][4] = s4;
                    if (jx == 0) {
                        float qm = fmaxf(q0, fmaxf(q1, q2));
                        float lse = qm + logf(__expf(q0 - qm) + __expf(q1 - qm) + __expf(q2 - qm));
                        float pl = -(xtL[row][2] * (q0 - lse) + xtL[row][3] * (q1 - lse) + xtL[row][4] * (q2 - lse));
                        float ol = ((sy + 1) < len) ? -logf(gp / S + 1e-6f) : 0.0f;
                        float* so = out + sy * 2560 + b * 5;
                        so[0] = s0; so[1] = s1; so[2] = s2; so[3] = s3; so[4] = s4;
                        redL[row] = pl; redL[32 + row] = ol;
                    }
                }
            }
            __syncthreads();
            if (jx == 0 && tid == 0) {
                float spl = 0, sol = 0;
                for (int r = 0; r < 32; ++r) { spl += redL[r]; sol += redL[32 + r]; }
                atomicAdd(out + 512001, spl * (1.0f / 102400.0f));
                atomicAdd(out + 512000, sol * (1.0f / 102400.0f));
            }
        }

        if (do_cell) {
            __syncthreads();
#pragma unroll
            for (int mt = 0; mt < 2; ++mt)
#pragma unroll
                for (int nt = 0; nt < 2; ++nt)
#pragma unroll
                    for (int r2 = 0; r2 < 4; ++r2)
                        gL[wv][mt * 16 + (lane >> 4) * 4 + r2][nt * 16 + (lane & 15)] = acc[mt][nt][r2];
            __syncthreads();
#pragma unroll
            for (int ii = 0; ii < 4; ++ii) {
                const int b = rq + ii * 8;
                const int gb = row0 + b;
                float gv[4];
#pragma unroll
                for (int g = 0; g < 4; ++g) {
                    float sum = gL[g][b][j] + zpre[gb * 2048 + g * 512 + j0 + j];
#pragma unroll
                    for (int i = 0; i < 5; ++i) sum += sxs[b][i] * dw[i][g];
                    gv[g] = sum;
                }
                float cv = c4[ii];
                cv = sigm(gv[1]) * cv + sigm(gv[0]) * tanhf(gv[2]);
                c4[ii] = cv;
                float hv = sigm(gv[3]) * tanhf(cv);
                const int gidx = gb * 512 + j0 + j;
                u16 hh = f2bf(hv);
                hn_hi[gidx] = hh;
                hn_lo[gidx] = f2bf(hv - bf2f(hh));
            }
            group_bar(mybar, 16u);   // h visible group-wide
        }
    }
}

extern "C" void kernel_launch(void* const* d_in, const int* in_sizes, int n_in,
                              void* d_out_, int out_size, void* d_ws, size_t ws_size,
                              hipStream_t stream) {
    const float* x         = (const float*)d_in[0];
    const int*   N_s       = (const int*)  d_in[1];
    const float* eps       = (const float*)d_in[2];
    const float* enc_Wih_f = (const float*)d_in[3];
    const float* enc_Whh_f = (const float*)d_in[4];
    const float* enc_b_f   = (const float*)d_in[5];
    const float* enc_Wih_b = (const float*)d_in[6];
    const float* enc_Whh_b = (const float*)d_in[7];
    const float* enc_b_b   = (const float*)d_in[8];
    const float* W_mu      = (const float*)d_in[9];
    const float* b_mu      = (const float*)d_in[10];
    const float* W_logvar  = (const float*)d_in[11];
    const float* b_logvar  = (const float*)d_in[12];
    const float* W_fc_in   = (const float*)d_in[13];
    const float* b_fc_in   = (const float*)d_in[14];
    const float* dec_Wih   = (const float*)d_in[15];
    const float* dec_Whh   = (const float*)d_in[16];
    const float* dec_b     = (const float*)d_in[17];
    const float* W_out     = (const float*)d_in[18];
    const float* b_out     = (const float*)d_in[19];
    float* out = (float*)d_out_;
    float* ws  = (float*)d_ws;

    float* c_d   = ws + 0;                    // 262144
    float* zpre  = ws + 262144;               // 1048576
    float* z     = ws + 1310720;              // 65536
    float* ybuf  = ws + 1376256;              // 65536
    unsigned* bar = (unsigned*)(ws + 1441792); // 1536 uints
    u16* U     = (u16*)(ws + 1443840);
    u16* he    = U;                   // 8 * 131072
    u16* hd    = U + 1048576;         // 4 * 262144
    u16* encT  = U + 2097152;         // 4 * 262144
    u16* decT  = U + 3145728;         // 2 * 1048576
    u16* woutT = U + 5242880;         // 2 * 65536

    hipMemsetAsync(he, 0, 4 * HE_BLK * sizeof(u16), stream);          // enc h buf0 (hi+lo, both dirs)
    hipMemsetAsync(bar, 0, 1536 * sizeof(unsigned), stream);          // barrier flags
    hipMemsetAsync(out + 509440, 0, 2562 * sizeof(float), stream);    // stroke row 199 + losses

    prep_split_T<<<1024, 256, 0, stream>>>(enc_Whh_f, encT,           encT + 262144,  256, 1024, 1024);
    prep_split_T<<<1024, 256, 0, stream>>>(enc_Whh_b, encT + 524288,  encT + 786432,  256, 1024, 1024);
    prep_split_T<<<4096, 256, 0, stream>>>(dec_Whh,   decT,           decT + 1048576, 512, 2048, 2048);
    prep_split_T<<<256,  256, 0, stream>>>(W_out,     woutT,          woutT + 65536,  512, 123, 128);

    enc_persist<<<256, 256, 0, stream>>>(x, enc_Wih_f, enc_b_f, enc_Wih_b, enc_b_b, encT, he, bar);
    latent1<<<32, 256, 0, stream>>>(he, W_mu, b_mu, W_logvar, b_logvar, eps, z, out);
    latent2<<<dim3(24, 32), 256, 0, stream>>>(z, W_fc_in, b_fc_in, dec_Wih, dec_b, hd, c_d, zpre);
    dec_persist<<<256, 256, 0, stream>>>(x, N_s, dec_Wih, b_out, decT, woutT, zpre, hd, c_d, ybuf, out, bar);
}